// Round 8
// baseline (126.293 us; speedup 1.0000x reference)
//
#include <hip/hip_runtime.h>
#include <hip/hip_cooperative_groups.h>

namespace cg = cooperative_groups;

#define X_H 4096
#define X_W 128
#define BATCH 4
#define CH 128
#define TT_OUT 2048
#define FF 64
#define EPS_GN 1e-3f
#define T_TILE 16

typedef float f4 __attribute__((ext_vector_type(4)));

// workspace float offsets
#define S1_OFF 0
#define SS_OFF (BATCH*TT_OUT)

// One cooperative kernel: phase 1 = per-(b,t) S1/SS stats; grid sync;
// phase 2 = in-block cumulative prefix + conv + norm + relu over all 128 ch.
// Grid: (TT_OUT/T_TILE = 128, 1, BATCH) = 512 blocks x 256 threads
//   -> 2 blocks/CU co-resident (8 waves/CU), safe for cooperative launch.
__global__ __launch_bounds__(256) void fused_kernel(const float* __restrict__ x,
        const float* __restrict__ w, const float* __restrict__ scale,
        float* __restrict__ ws, float* __restrict__ out) {
    __shared__ float wlds[CH*9];     // raw weights, staged once, reused phase 2
    __shared__ float sl[CH];
    __shared__ float Ml[81];
    __shared__ float Wl[9];
    __shared__ float redA[4], redB[4], redC[4];

    int tid = threadIdx.x;
    int lane = tid & 63;
    int wv = tid >> 6;
    int bid = blockIdx.z * 128 + blockIdx.x;     // 0..511

    // ---- stage weights + scale into LDS ----
#pragma unroll
    for (int i = tid; i < CH*9; i += 256) wlds[i] = w[i];
    if (tid < CH) sl[tid] = scale[tid];
    __syncthreads();

    // ---- weight reductions: Wsum (9), M = sum_c w_c w_c^T (81) ----
    if (tid < 81) {
        int j = tid / 9, k = tid % 9;
        float acc = 0.f;
#pragma unroll 8
        for (int c = 0; c < CH; ++c) acc = fmaf(wlds[c*9 + j], wlds[c*9 + k], acc);
        Ml[tid] = acc;
    } else if (tid < 90) {
        int k = tid - 81;
        float acc = 0.f;
#pragma unroll 8
        for (int c = 0; c < CH; ++c) acc += wlds[c*9 + k];
        Wl[k] = acc;
    }
    __syncthreads();

    // ================= phase 1: stats for 16 (b,t) rows =================
    {
        int fq = tid & 15;
        int tr = tid >> 4;
        int gt = bid * 16 + tr;              // b*2048 + t
        int t = gt & (TT_OUT - 1);
        int b = gt >> 11;
        const float* xb = x + (size_t)b * (X_H * X_W);

        float xr[3][9];
        int r0 = 2*t - 1;
#pragma unroll
        for (int kh = 0; kh < 3; ++kh) {
            int r = r0 + kh;
            if (r >= 0 && r < X_H) {
                const float* rp = xb + (size_t)r * X_W + 8*fq;
                f4 v0 = *(const f4*)rp;
                f4 v1 = *(const f4*)(rp + 4);
                xr[kh][0]=v0.x; xr[kh][1]=v0.y; xr[kh][2]=v0.z; xr[kh][3]=v0.w;
                xr[kh][4]=v1.x; xr[kh][5]=v1.y; xr[kh][6]=v1.z; xr[kh][7]=v1.w;
                xr[kh][8] = (fq == 15) ? 0.f : rp[8];
            } else {
#pragma unroll
                for (int k = 0; k < 9; ++k) xr[kh][k] = 0.f;
            }
        }

        float s1 = 0.f, ss = 0.f;
#pragma unroll
        for (int jf = 0; jf < 4; ++jf) {
            float tv[9];
#pragma unroll
            for (int kh = 0; kh < 3; ++kh)
#pragma unroll
                for (int kw = 0; kw < 3; ++kw)
                    tv[kh*3+kw] = xr[kh][2*jf + kw];
#pragma unroll
            for (int k = 0; k < 9; ++k) s1 = fmaf(Wl[k], tv[k], s1);
#pragma unroll
            for (int j = 0; j < 9; ++j) {
                float tj = 0.f;
#pragma unroll
                for (int k = 0; k < 9; ++k) tj = fmaf(Ml[j*9+k], tv[k], tj);
                ss = fmaf(tv[j], tj, ss);
            }
        }
#pragma unroll
        for (int off = 1; off < 16; off <<= 1) {
            s1 += __shfl_xor(s1, off);
            ss += __shfl_xor(ss, off);
        }
        if (fq == 0) {
            ws[S1_OFF + gt] = s1;
            ws[SS_OFF + gt] = ss;
        }
    }

    __threadfence();
    cg::this_grid().sync();

    // ================= phase 2: out tile (b, t0..t0+15, all 128 ch) ======
    int b = blockIdx.z;
    int t0 = blockIdx.x * T_TILE;

    const float* S1 = ws + S1_OFF + b*TT_OUT;
    const float* SS = ws + SS_OFF + b*TT_OUT;
    const f4* S1v = (const f4*)S1;
    const f4* SSv = (const f4*)SS;
    f4 a0 = S1v[tid*2], a1 = S1v[tid*2+1];
    f4 e0 = SSv[tid*2], e1 = SSv[tid*2+1];
    float s1l[8] = {a0.x,a0.y,a0.z,a0.w,a1.x,a1.y,a1.z,a1.w};
    float ssl[8] = {e0.x,e0.y,e0.z,e0.w,e1.x,e1.y,e1.z,e1.w};
    int tau0 = tid * 8;
    float tot = 0.f;
#pragma unroll
    for (int i = 0; i < 8; ++i) {
        tot += (tau0 + i < t0) ? s1l[i] : 0.f;
    }
    float incl = tot;
#pragma unroll
    for (int off = 1; off < 64; off <<= 1) {
        float n = __shfl_up(incl, off);
        if (lane >= off) incl += n;
    }
    if (lane == 63) redA[wv] = incl;
    __syncthreads();
    float woff = 0.f;
    for (int w2 = 0; w2 < wv; ++w2) woff += redA[w2];
    float prefix = woff + incl - tot;      // exclusive prefix of masked S1

    float run = prefix;
    float sqp = 0.f;
#pragma unroll
    for (int i = 0; i < 8; ++i) {
        if (tau0 + i < t0) {
            run += s1l[i];
            float cnt = (float)(tau0 + i + 1) * 8192.f;
            float mu = run / cnt;
            sqp += ssl[i] - 2.f*mu*s1l[i] + 8192.f*mu*mu;
        }
    }
    float r1 = tot, r2 = sqp;
#pragma unroll
    for (int off = 32; off > 0; off >>= 1) {
        r1 += __shfl_xor(r1, off);
        r2 += __shfl_xor(r2, off);
    }
    if (lane == 0) { redB[wv] = r1; redC[wv] = r2; }
    __syncthreads();
    float base1 = redB[0] + redB[1] + redB[2] + redB[3];
    float base_sq = redC[0] + redC[1] + redC[2] + redC[3];

    // serial 16-step tile prefix (uniform loads)
    int tr = tid >> 4;
    float run16 = base1, sq16 = base_sq;
    float mu_t = 0.f, istd_t = 0.f;
#pragma unroll
    for (int i = 0; i < T_TILE; ++i) {
        int t = t0 + i;
        float s1t = S1[t];
        float sst = SS[t];
        run16 += s1t;
        float cnt = (float)(t + 1) * 8192.f;
        float mu = run16 / cnt;
        sq16 += sst - 2.f*mu*s1t + 8192.f*mu*mu;
        if (i == tr) { mu_t = mu; istd_t = rsqrtf(sq16 / cnt + EPS_GN); }
    }

    // conv + norm + relu over all 128 channels
    int fq = tid & 15;          // 4 f's: f = 4*fq .. 4*fq+3
    int t = t0 + tr;
    const float* xb = x + (size_t)b * (X_H * X_W);

    float xr[3][9];
    int r0 = 2*t - 1;
#pragma unroll
    for (int kh = 0; kh < 3; ++kh) {
        int r = r0 + kh;
        if (r >= 0 && r < X_H) {
            const float* rp = xb + (size_t)r * X_W + 8*fq;
            f4 v0 = *(const f4*)rp;
            f4 v1 = *(const f4*)(rp + 4);
            xr[kh][0]=v0.x; xr[kh][1]=v0.y; xr[kh][2]=v0.z; xr[kh][3]=v0.w;
            xr[kh][4]=v1.x; xr[kh][5]=v1.y; xr[kh][6]=v1.z; xr[kh][7]=v1.w;
            xr[kh][8] = (fq == 15) ? 0.f : rp[8];
        } else {
#pragma unroll
            for (int k = 0; k < 9; ++k) xr[kh][k] = 0.f;
        }
    }

    float* ob = out + (((size_t)b * CH * TT_OUT + t) * FF + 4*fq);
#pragma unroll 4
    for (int c = 0; c < CH; ++c) {
        float a  = istd_t * sl[c];
        float nb = -mu_t * a;
        f4 v;
#pragma unroll
        for (int jf = 0; jf < 4; ++jf) {
            float h = 0.f;
#pragma unroll
            for (int kh = 0; kh < 3; ++kh)
#pragma unroll
                for (int kw = 0; kw < 3; ++kw)
                    h = fmaf(wlds[c*9 + kh*3+kw], xr[kh][2*jf + kw], h);
            v[jf] = fmaxf(fmaf(h, a, nb), 0.f);
        }
        *(f4*)(ob + (size_t)c * (TT_OUT * FF)) = v;
    }
}

extern "C" void kernel_launch(void* const* d_in, const int* in_sizes, int n_in,
                              void* d_out, int out_size, void* d_ws, size_t ws_size,
                              hipStream_t stream) {
    const float* x     = (const float*)d_in[0];
    const float* w     = (const float*)d_in[1];
    const float* scale = (const float*)d_in[2];
    float* out = (float*)d_out;
    float* ws  = (float*)d_ws;

    void* args[] = {(void*)&x, (void*)&w, (void*)&scale, (void*)&ws, (void*)&out};
    hipLaunchCooperativeKernel((const void*)fused_kernel,
                               dim3(TT_OUT/T_TILE, 1, BATCH), dim3(256, 1, 1),
                               args, 0, stream);
}

// Round 9
// 69.409 us; speedup vs baseline: 1.8195x; 1.8195x over previous
//
#include <hip/hip_runtime.h>

#define X_H 4096
#define X_W 128
#define BATCH 4
#define CH 128
#define TT_OUT 2048
#define FF 64
#define EPS_GN 1e-3f

typedef float f4 __attribute__((ext_vector_type(4)));

// workspace float offsets
#define S1_OFF 0
#define SS_OFF (BATCH*TT_OUT)

// ---------------- kernel 1: per-(b,t) S1, SS (prep fused via LDS) ----------
__global__ __launch_bounds__(256) void stats_kernel(const float* __restrict__ x,
                                                    const float* __restrict__ w,
                                                    float* __restrict__ ws) {
    __shared__ float wlds[CH*9];
    __shared__ float Ml[81];
    __shared__ float Wl[9];
    int tid = threadIdx.x;
#pragma unroll
    for (int i = tid; i < CH*9; i += 256) wlds[i] = w[i];
    __syncthreads();
    if (tid < 81) {
        int j = tid / 9, k = tid % 9;
        float acc = 0.f;
#pragma unroll 8
        for (int c = 0; c < CH; ++c) acc = fmaf(wlds[c*9 + j], wlds[c*9 + k], acc);
        Ml[tid] = acc;
    } else if (tid < 90) {
        int k = tid - 81;
        float acc = 0.f;
#pragma unroll 8
        for (int c = 0; c < CH; ++c) acc += wlds[c*9 + k];
        Wl[k] = acc;
    }
    __syncthreads();

    int fq = tid & 15;
    int tr = tid >> 4;
    int gt = blockIdx.x * 16 + tr;          // b*2048 + t
    int t = gt & (TT_OUT - 1);
    int b = gt >> 11;
    const float* xb = x + (size_t)b * (X_H * X_W);

    float xr[3][9];
    int r0 = 2*t - 1;
#pragma unroll
    for (int kh = 0; kh < 3; ++kh) {
        int r = r0 + kh;
        if (r >= 0 && r < X_H) {
            const float* rp = xb + (size_t)r * X_W + 8*fq;
            f4 v0 = *(const f4*)rp;
            f4 v1 = *(const f4*)(rp + 4);
            xr[kh][0]=v0.x; xr[kh][1]=v0.y; xr[kh][2]=v0.z; xr[kh][3]=v0.w;
            xr[kh][4]=v1.x; xr[kh][5]=v1.y; xr[kh][6]=v1.z; xr[kh][7]=v1.w;
            xr[kh][8] = (fq == 15) ? 0.f : rp[8];
        } else {
#pragma unroll
            for (int k = 0; k < 9; ++k) xr[kh][k] = 0.f;
        }
    }

    float s1 = 0.f, ss = 0.f;
#pragma unroll
    for (int jf = 0; jf < 4; ++jf) {
        float tv[9];
#pragma unroll
        for (int kh = 0; kh < 3; ++kh)
#pragma unroll
            for (int kw = 0; kw < 3; ++kw)
                tv[kh*3+kw] = xr[kh][2*jf + kw];
#pragma unroll
        for (int k = 0; k < 9; ++k) s1 = fmaf(Wl[k], tv[k], s1);
#pragma unroll
        for (int j = 0; j < 9; ++j) {
            float tj = 0.f;
#pragma unroll
            for (int k = 0; k < 9; ++k) tj = fmaf(Ml[j*9+k], tv[k], tj);
            ss = fmaf(tv[j], tj, ss);
        }
    }
#pragma unroll
    for (int off = 1; off < 16; off <<= 1) {
        s1 += __shfl_xor(s1, off);
        ss += __shfl_xor(ss, off);
    }
    if (fq == 0) {
        ws[S1_OFF + gt] = s1;
        ws[SS_OFF + gt] = ss;
    }
}

// ------- kernel 2: in-block cumulative stats + conv + norm + relu ---------
#define T_TILE 16
#define CG 64
__global__ __launch_bounds__(256) void out_kernel(const float* __restrict__ x,
        const float* __restrict__ w, const float* __restrict__ scale,
        const float* __restrict__ ws, float* __restrict__ out) {
    __shared__ float wl[CG][9];
    __shared__ float sl[CG];
    __shared__ float redA[4], redB[4], redC[4];
    int tid = threadIdx.x;
    int lane = tid & 63;
    int wv = tid >> 6;
    int b = blockIdx.z;
    int c0 = blockIdx.y * CG;
    int t0 = blockIdx.x * T_TILE;

    for (int i = tid; i < CG*9; i += 256) wl[i/9][i%9] = w[c0*9 + i];
    if (tid < CG) sl[tid] = scale[c0 + tid];

    // ---- recompute cumulative prefix over [0, t0) from S1/SS ----
    // only threads whose 8-element segment starts below t0 need data
    const float* S1 = ws + S1_OFF + b*TT_OUT;
    const float* SS = ws + SS_OFF + b*TT_OUT;
    const f4* S1v = (const f4*)S1;
    const f4* SSv = (const f4*)SS;
    int tau0 = tid * 8;
    float s1l[8], ssl[8];
    if (tau0 < t0) {
        f4 a0 = S1v[tid*2], a1 = S1v[tid*2+1];
        f4 e0 = SSv[tid*2], e1 = SSv[tid*2+1];
        s1l[0]=a0.x; s1l[1]=a0.y; s1l[2]=a0.z; s1l[3]=a0.w;
        s1l[4]=a1.x; s1l[5]=a1.y; s1l[6]=a1.z; s1l[7]=a1.w;
        ssl[0]=e0.x; ssl[1]=e0.y; ssl[2]=e0.z; ssl[3]=e0.w;
        ssl[4]=e1.x; ssl[5]=e1.y; ssl[6]=e1.z; ssl[7]=e1.w;
    } else {
#pragma unroll
        for (int i = 0; i < 8; ++i) { s1l[i] = 0.f; ssl[i] = 0.f; }
    }
    float tot = 0.f;
#pragma unroll
    for (int i = 0; i < 8; ++i) {
        tot += (tau0 + i < t0) ? s1l[i] : 0.f;
    }
    // wave inclusive scan of tot
    float incl = tot;
#pragma unroll
    for (int off = 1; off < 64; off <<= 1) {
        float n = __shfl_up(incl, off);
        if (lane >= off) incl += n;
    }
    if (lane == 63) redA[wv] = incl;
    __syncthreads();
    float woff = 0.f;
    for (int w2 = 0; w2 < wv; ++w2) woff += redA[w2];
    float prefix = woff + incl - tot;      // exclusive prefix of masked S1

    // per-thread: accumulate sq over its masked taus (running mean)
    float run = prefix;
    float sqp = 0.f;
#pragma unroll
    for (int i = 0; i < 8; ++i) {
        if (tau0 + i < t0) {
            run += s1l[i];
            float cnt = (float)(tau0 + i + 1) * 8192.f;
            float mu = run / cnt;
            sqp += ssl[i] - 2.f*mu*s1l[i] + 8192.f*mu*mu;
        }
    }
    // block reduce
    float r1 = tot, r2 = sqp;
#pragma unroll
    for (int off = 32; off > 0; off >>= 1) {
        r1 += __shfl_xor(r1, off);
        r2 += __shfl_xor(r2, off);
    }
    if (lane == 0) { redB[wv] = r1; redC[wv] = r2; }
    __syncthreads();
    float base1 = redB[0] + redB[1] + redB[2] + redB[3];
    float base_sq = redC[0] + redC[1] + redC[2] + redC[3];

    // ---- serial 16-step tile prefix (uniform loads) ----
    int tr = tid >> 4;
    float run16 = base1, sq16 = base_sq;
    float mu_t = 0.f, istd_t = 0.f;
#pragma unroll
    for (int i = 0; i < T_TILE; ++i) {
        int t = t0 + i;
        float s1t = S1[t];
        float sst = SS[t];
        run16 += s1t;
        float cnt = (float)(t + 1) * 8192.f;
        float mu = run16 / cnt;
        sq16 += sst - 2.f*mu*s1t + 8192.f*mu*mu;
        if (i == tr) { mu_t = mu; istd_t = rsqrtf(sq16 / cnt + EPS_GN); }
    }

    // ---- conv + norm + relu ----
    int fq = tid & 15;          // 4 f's: f = 4*fq .. 4*fq+3
    int t = t0 + tr;
    const float* xb = x + (size_t)b * (X_H * X_W);

    float xr[3][9];
    int r0 = 2*t - 1;
#pragma unroll
    for (int kh = 0; kh < 3; ++kh) {
        int r = r0 + kh;
        if (r >= 0 && r < X_H) {
            const float* rp = xb + (size_t)r * X_W + 8*fq;
            f4 v0 = *(const f4*)rp;
            f4 v1 = *(const f4*)(rp + 4);
            xr[kh][0]=v0.x; xr[kh][1]=v0.y; xr[kh][2]=v0.z; xr[kh][3]=v0.w;
            xr[kh][4]=v1.x; xr[kh][5]=v1.y; xr[kh][6]=v1.z; xr[kh][7]=v1.w;
            xr[kh][8] = (fq == 15) ? 0.f : rp[8];
        } else {
#pragma unroll
            for (int k = 0; k < 9; ++k) xr[kh][k] = 0.f;
        }
    }

    float* ob = out + (((size_t)(b*CH + c0) * TT_OUT + t) * FF + 4*fq);
#pragma unroll 4
    for (int c = 0; c < CG; ++c) {
        float a  = istd_t * sl[c];
        float nb = -mu_t * a;
        f4 v;
#pragma unroll
        for (int jf = 0; jf < 4; ++jf) {
            float h = 0.f;
#pragma unroll
            for (int kh = 0; kh < 3; ++kh)
#pragma unroll
                for (int kw = 0; kw < 3; ++kw)
                    h = fmaf(wl[c][kh*3+kw], xr[kh][2*jf + kw], h);
            v[jf] = fmaxf(fmaf(h, a, nb), 0.f);
        }
        __builtin_nontemporal_store(v, (f4*)(ob + (size_t)c * (TT_OUT * FF)));
    }
}

extern "C" void kernel_launch(void* const* d_in, const int* in_sizes, int n_in,
                              void* d_out, int out_size, void* d_ws, size_t ws_size,
                              hipStream_t stream) {
    const float* x     = (const float*)d_in[0];
    const float* w     = (const float*)d_in[1];
    const float* scale = (const float*)d_in[2];
    float* out = (float*)d_out;
    float* ws  = (float*)d_ws;

    stats_kernel<<<(BATCH*TT_OUT)/16, 256, 0, stream>>>(x, w, ws);
    out_kernel<<<dim3(TT_OUT/T_TILE, CH/CG, BATCH), 256, 0, stream>>>(x, w, scale, ws, out);
}

// Round 10
// 58.779 us; speedup vs baseline: 2.1486x; 1.1809x over previous
//
#include <hip/hip_runtime.h>

#define X_H 4096
#define X_W 128
#define BATCH 4
#define CH 128
#define TT_OUT 2048
#define FF 64
#define EPS_GN 1e-3f

typedef float f4 __attribute__((ext_vector_type(4)));

// workspace float offsets
#define S1_OFF 0
#define SS_OFF (BATCH*TT_OUT)

// ---------------- kernel 1: per-(b,t) S1, SS (prep fused via LDS) ----------
__global__ __launch_bounds__(256) void stats_kernel(const float* __restrict__ x,
                                                    const float* __restrict__ w,
                                                    float* __restrict__ ws) {
    __shared__ float wlds[CH*9];
    __shared__ float Ml[81];
    __shared__ float Wl[9];
    int tid = threadIdx.x;
#pragma unroll
    for (int i = tid; i < CH*9; i += 256) wlds[i] = w[i];
    __syncthreads();
    if (tid < 81) {
        int j = tid / 9, k = tid % 9;
        float acc = 0.f;
#pragma unroll 8
        for (int c = 0; c < CH; ++c) acc = fmaf(wlds[c*9 + j], wlds[c*9 + k], acc);
        Ml[tid] = acc;
    } else if (tid < 90) {
        int k = tid - 81;
        float acc = 0.f;
#pragma unroll 8
        for (int c = 0; c < CH; ++c) acc += wlds[c*9 + k];
        Wl[k] = acc;
    }
    __syncthreads();

    int fq = tid & 15;
    int tr = tid >> 4;
    int gt = blockIdx.x * 16 + tr;          // b*2048 + t
    int t = gt & (TT_OUT - 1);
    int b = gt >> 11;
    const float* xb = x + (size_t)b * (X_H * X_W);

    float xr[3][9];
    int r0 = 2*t - 1;
#pragma unroll
    for (int kh = 0; kh < 3; ++kh) {
        int r = r0 + kh;
        if (r >= 0 && r < X_H) {
            const float* rp = xb + (size_t)r * X_W + 8*fq;
            f4 v0 = *(const f4*)rp;
            f4 v1 = *(const f4*)(rp + 4);
            xr[kh][0]=v0.x; xr[kh][1]=v0.y; xr[kh][2]=v0.z; xr[kh][3]=v0.w;
            xr[kh][4]=v1.x; xr[kh][5]=v1.y; xr[kh][6]=v1.z; xr[kh][7]=v1.w;
            xr[kh][8] = (fq == 15) ? 0.f : rp[8];
        } else {
#pragma unroll
            for (int k = 0; k < 9; ++k) xr[kh][k] = 0.f;
        }
    }

    float s1 = 0.f, ss = 0.f;
#pragma unroll
    for (int jf = 0; jf < 4; ++jf) {
        float tv[9];
#pragma unroll
        for (int kh = 0; kh < 3; ++kh)
#pragma unroll
            for (int kw = 0; kw < 3; ++kw)
                tv[kh*3+kw] = xr[kh][2*jf + kw];
#pragma unroll
        for (int k = 0; k < 9; ++k) s1 = fmaf(Wl[k], tv[k], s1);
#pragma unroll
        for (int j = 0; j < 9; ++j) {
            float tj = 0.f;
#pragma unroll
            for (int k = 0; k < 9; ++k) tj = fmaf(Ml[j*9+k], tv[k], tj);
            ss = fmaf(tv[j], tj, ss);
        }
    }
#pragma unroll
    for (int off = 1; off < 16; off <<= 1) {
        s1 += __shfl_xor(s1, off);
        ss += __shfl_xor(ss, off);
    }
    if (fq == 0) {
        ws[S1_OFF + gt] = s1;
        ws[SS_OFF + gt] = ss;
    }
}

// ------- kernel 2: in-block cumulative stats + conv + norm + relu ---------
#define T_TILE 16
#define CG 32
__global__ __launch_bounds__(256) void out_kernel(const float* __restrict__ x,
        const float* __restrict__ w, const float* __restrict__ scale,
        const float* __restrict__ ws, float* __restrict__ out) {
    __shared__ float wl[CG][9];
    __shared__ float sl[CG];
    __shared__ float redA[4], redB[4], redC[4];
    int tid = threadIdx.x;
    int lane = tid & 63;
    int wv = tid >> 6;
    int b = blockIdx.z;
    int c0 = blockIdx.y * CG;
    int t0 = blockIdx.x * T_TILE;

    for (int i = tid; i < CG*9; i += 256) wl[i/9][i%9] = w[c0*9 + i];
    if (tid < CG) sl[tid] = scale[c0 + tid];

    // ---- early-issue conv tap loads (overlap with scan below) ----
    int fq = tid & 15;          // 4 f's: f = 4*fq .. 4*fq+3
    int tr = tid >> 4;          // 0..15
    int t = t0 + tr;
    const float* xb = x + (size_t)b * (X_H * X_W);
    float xr[3][9];
    {
        int r0 = 2*t - 1;
#pragma unroll
        for (int kh = 0; kh < 3; ++kh) {
            int r = r0 + kh;
            if (r >= 0 && r < X_H) {
                const float* rp = xb + (size_t)r * X_W + 8*fq;
                f4 v0 = *(const f4*)rp;
                f4 v1 = *(const f4*)(rp + 4);
                xr[kh][0]=v0.x; xr[kh][1]=v0.y; xr[kh][2]=v0.z; xr[kh][3]=v0.w;
                xr[kh][4]=v1.x; xr[kh][5]=v1.y; xr[kh][6]=v1.z; xr[kh][7]=v1.w;
                xr[kh][8] = (fq == 15) ? 0.f : rp[8];
            } else {
#pragma unroll
                for (int k = 0; k < 9; ++k) xr[kh][k] = 0.f;
            }
        }
    }

    // ---- recompute cumulative prefix over [0, t0) from S1/SS ----
    const float* S1 = ws + S1_OFF + b*TT_OUT;
    const float* SS = ws + SS_OFF + b*TT_OUT;
    const f4* S1v = (const f4*)S1;
    const f4* SSv = (const f4*)SS;
    f4 a0 = S1v[tid*2], a1 = S1v[tid*2+1];
    f4 e0 = SSv[tid*2], e1 = SSv[tid*2+1];
    float s1l[8] = {a0.x,a0.y,a0.z,a0.w,a1.x,a1.y,a1.z,a1.w};
    float ssl[8] = {e0.x,e0.y,e0.z,e0.w,e1.x,e1.y,e1.z,e1.w};
    int tau0 = tid * 8;
    float tot = 0.f;
#pragma unroll
    for (int i = 0; i < 8; ++i) {
        tot += (tau0 + i < t0) ? s1l[i] : 0.f;
    }
    // wave inclusive scan of tot
    float incl = tot;
#pragma unroll
    for (int off = 1; off < 64; off <<= 1) {
        float n = __shfl_up(incl, off);
        if (lane >= off) incl += n;
    }
    if (lane == 63) redA[wv] = incl;
    __syncthreads();
    float woff = 0.f;
    for (int w2 = 0; w2 < wv; ++w2) woff += redA[w2];
    float prefix = woff + incl - tot;      // exclusive prefix of masked S1

    // per-thread: accumulate sq over its masked taus (running mean)
    float run = prefix;
    float sqp = 0.f;
#pragma unroll
    for (int i = 0; i < 8; ++i) {
        if (tau0 + i < t0) {
            run += s1l[i];
            float cnt = (float)(tau0 + i + 1) * 8192.f;
            float mu = run / cnt;
            sqp += ssl[i] - 2.f*mu*s1l[i] + 8192.f*mu*mu;
        }
    }
    // block reduce
    float r1 = tot, r2 = sqp;
#pragma unroll
    for (int off = 32; off > 0; off >>= 1) {
        r1 += __shfl_xor(r1, off);
        r2 += __shfl_xor(r2, off);
    }
    if (lane == 0) { redB[wv] = r1; redC[wv] = r2; }
    __syncthreads();
    float base1 = redB[0] + redB[1] + redB[2] + redB[3];
    float base_sq = redC[0] + redC[1] + redC[2] + redC[3];

    // ---- parallel tile prefix: lanes 0..15 via shuffle scans ----
    float s1t = 0.f, sst = 0.f;
    if (lane < T_TILE) { s1t = S1[t0 + lane]; sst = SS[t0 + lane]; }
    float cs = s1t;
#pragma unroll
    for (int off = 1; off < 16; off <<= 1) {
        float n = __shfl_up(cs, off);
        if (lane >= off) cs += n;
    }
    float cnt_l = (float)(t0 + lane + 1) * 8192.f;
    float mu_l = (base1 + cs) / cnt_l;
    float term = sst - 2.f*mu_l*s1t + 8192.f*mu_l*mu_l;
    float ct = term;
#pragma unroll
    for (int off = 1; off < 16; off <<= 1) {
        float n = __shfl_up(ct, off);
        if (lane >= off) ct += n;
    }
    float istd_l = rsqrtf((base_sq + ct) / cnt_l + EPS_GN);
    float mu_t = __shfl(mu_l, tr);
    float istd_t = __shfl(istd_l, tr);

    // ---- conv + norm + relu ----
    float* ob = out + (((size_t)(b*CH + c0) * TT_OUT + t) * FF + 4*fq);
#pragma unroll 4
    for (int c = 0; c < CG; ++c) {
        float a  = istd_t * sl[c];
        float nb = -mu_t * a;
        f4 v;
#pragma unroll
        for (int jf = 0; jf < 4; ++jf) {
            float h = 0.f;
#pragma unroll
            for (int kh = 0; kh < 3; ++kh)
#pragma unroll
                for (int kw = 0; kw < 3; ++kw)
                    h = fmaf(wl[c][kh*3+kw], xr[kh][2*jf + kw], h);
            v[jf] = fmaxf(fmaf(h, a, nb), 0.f);
        }
        *(f4*)(ob + (size_t)c * (TT_OUT * FF)) = v;
    }
}

extern "C" void kernel_launch(void* const* d_in, const int* in_sizes, int n_in,
                              void* d_out, int out_size, void* d_ws, size_t ws_size,
                              hipStream_t stream) {
    const float* x     = (const float*)d_in[0];
    const float* w     = (const float*)d_in[1];
    const float* scale = (const float*)d_in[2];
    float* out = (float*)d_out;
    float* ws  = (float*)d_ws;

    stats_kernel<<<(BATCH*TT_OUT)/16, 256, 0, stream>>>(x, w, ws);
    out_kernel<<<dim3(TT_OUT/T_TILE, CH/CG, BATCH), 256, 0, stream>>>(x, w, scale, ws, out);
}